// Round 12
// baseline (162.791 us; speedup 1.0000x reference)
//
#include <hip/hip_runtime.h>

#define NGRAPH 4096
#define NNODE  64
#define NDIM   128
#define NFP    2048
#define NLAYER 3
#define PH 136   // sh pitch (bf16): 68 dwords === 4 mod 32 -> bank-uniform b128 row reads

typedef __attribute__((ext_vector_type(8))) short short8;
typedef __attribute__((ext_vector_type(4))) float f32x4;
typedef __bf16 bf16x2 __attribute__((ext_vector_type(2)));

union S8 { short8 s8; unsigned d[4]; };

static __device__ inline ushort f2bf(float f) {  // RNE fp32 -> bf16 (fallback path)
  unsigned u = __float_as_uint(f);
  u += 0x7FFF + ((u >> 16) & 1);
  return (ushort)(u >> 16);
}

// packed fp32x2 -> bf16x2 in one HW instr on gfx950 (v_cvt_pk_bf16_f32)
static __device__ inline unsigned pkbf(float x, float y) {
#if __has_builtin(__builtin_amdgcn_cvt_pk_bf16_f32)
  bf16x2 v = __builtin_amdgcn_cvt_pk_bf16_f32(x, y);
  return __builtin_bit_cast(unsigned, v);
#else
  return (unsigned)f2bf(x) | ((unsigned)f2bf(y) << 16);
#endif
}

// W in bf16, native [l][k_out][d] layout (B-frag reads W rows directly).
__device__ __align__(16) ushort g_wbf[NLAYER * NDIM * NDIM];
// emb in bf16: gather in the hot kernel becomes a pure b128 copy.
__device__ __align__(16) ushort g_ebf[NFP * NDIM];   // 512 KB

__global__ __launch_bounds__(256) void convert_w(const float* __restrict__ W) {
  int i = blockIdx.x * 256 + threadIdx.x;   // 192 blocks, exact
  g_wbf[i] = f2bf(W[i]);
}

__global__ __launch_bounds__(256) void convert_emb(const float* __restrict__ emb) {
  int i = blockIdx.x * 256 + threadIdx.x;   // 1024 blocks, exact
  g_ebf[i] = f2bf(emb[i]);
}

// R20 = the proven micro-wins combined, + setprio:
//  - R13's ping-pong layer structure (1 barrier/layer; h-write overlaps other
//    waves' m1 instead of stalling at a pre-write barrier); adj staged into
//    sh1 (pong, dead until layer-0 output), 34.8 KB LDS.
//  - R19's transpose: permlane16_swap pre-mix + single bijective bpermute
//    address (16 bperm + 8 swap /wave-layer; verified correct, conflicts
//    7.9e6 -> 6.3e6).
//  - R16's bf16 g_ebf gather (pure b128 copy prologue).
//  - s_setprio(1) around m1->transpose->m2 (T5): blocks are independent
//    graphs at different phases on the same CU -> attn-like role diversity
//    (m191 +4-7%), not GEMM lockstep (m190 null).
// Calibration from R19: DS-pipe ~55% busy; each removed/overlapped DS cycle
// returns ~25% of serial value.  (256,4): 128-VGPR cap (spill rule R10/R15).
__global__ __launch_bounds__(256, 4) void mpnn_mfma(
    const int* __restrict__ fps, const float* __restrict__ adj,
    const float* __restrict__ emb, const float* __restrict__ bias,
    float* __restrict__ out) {
  __shared__ __align__(16) ushort sh0[NNODE * PH];    // h ping  17408 B
  __shared__ __align__(16) ushort sh1[NNODE * PH];    // adj stage -> h pong  17408 B

  const int g    = blockIdx.x;
  const int t    = threadIdx.x;
  const int w    = t >> 6;        // wave 0..3
  const int lane = t & 63;
  const int r    = lane & 15;     // MFMA row/col index
  const int q    = lane >> 4;     // quad 0..3
  const int n0   = w << 5;        // wave's 32-wide kout region (m1) == d region (m2)

  // single bijective bpermute address for the permlane-prepped transpose:
  // dest(r,q) pulls lane r + 32*(q&1) + 16*(q>>1)  (byte addr <<2)
  const int addrA = (r + 32 * (q & 1) + 16 * (q >> 1)) << 2;

  // ---- gather h0 = bf16 emb rows -> sh0 (pure b128 copy) ----
  const int* fg = fps + g * NNODE;
#pragma unroll
  for (int it = 0; it < 4; ++it) {
    int idx = it * 256 + t;               // 1024 b128s
    int n = idx >> 4;
    int c = (idx & 15) << 3;
    short8 v = *(const short8*)(g_ebf + fg[n] * NDIM + c);
    *(short8*)(sh0 + n * PH + c) = v;
  }

  // ---- adjacency -> sh1: bf16(I + A), staged once, cooperatively coalesced ----
  const float* adjg = adj + (size_t)g * NNODE * NNODE;
#pragma unroll
  for (int it = 0; it < 4; ++it) {
    int idx = it * 256 + t;               // 1024 float4s
    int n = idx >> 4;
    int c = (idx & 15) << 2;
    float4 v = *(const float4*)(adjg + n * NNODE + c);
    v.x += (n == c + 0) ? 1.0f : 0.0f;    // fold residual: I + A
    v.y += (n == c + 1) ? 1.0f : 0.0f;
    v.z += (n == c + 2) ? 1.0f : 0.0f;
    v.w += (n == c + 3) ? 1.0f : 0.0f;
    uint2 u = {pkbf(v.x, v.y), pkbf(v.z, v.w)};
    *(uint2*)(sh1 + n * PH + c) = u;
  }

  // ---- bias for all layers, both slabs -> registers ----
  float bv[NLAYER][2];
#pragma unroll
  for (int l = 0; l < NLAYER; ++l) {
    bv[l][0] = bias[l * NDIM + n0 + r];
    bv[l][1] = bias[l * NDIM + n0 + 16 + r];
  }

  __syncthreads();   // staging visible (sh0: h0, sh1: I+A)

  // ---- (I+A) B-frags -> registers, once per block (layer-invariant) ----
  // fbr[kh][nt] lane(r,q): (I+A)[node'=nt*16+r][node=kh*32+8q+e]
  short8 fbr[2][4];
#pragma unroll
  for (int kh = 0; kh < 2; ++kh)
#pragma unroll
    for (int nt = 0; nt < 4; ++nt)
      fbr[kh][nt] = *(const short8*)(sh1 + (nt * 16 + r) * PH + kh * 32 + 8 * q);
  __syncthreads();   // all fbr reads done before layer-0 m2 writes recycle sh1

#pragma unroll 1   // real loop: avoid cross-layer load hoisting -> spill (R6 lesson)
  for (int l = 0; l < NLAYER; ++l) {
    const ushort* shr = (l & 1) ? sh1 : sh0;   // read buffer
    ushort*       shw = (l & 1) ? sh0 : sh1;   // write buffer (ping-pong)
    const ushort* Wl  = g_wbf + l * NDIM * NDIM;

    __builtin_amdgcn_s_setprio(1);   // favor compute-phase waves on this CU

    // ---- m1: z[node][n0-region(32)] = relu(h * W^T + b), two 16-slabs ----
    f32x4 acc[2][4];
#pragma unroll
    for (int s = 0; s < 2; ++s)
#pragma unroll
      for (int mt = 0; mt < 4; ++mt)
        acc[s][mt] = (f32x4){bv[l][s], bv[l][s], bv[l][s], bv[l][s]};
#pragma unroll
    for (int k0 = 0; k0 < NDIM; k0 += 32) {
      short8 ah[4];                       // loaded ONCE, feeds both slabs
#pragma unroll
      for (int mt = 0; mt < 4; ++mt)
        ah[mt] = *(const short8*)(shr + (mt * 16 + r) * PH + k0 + 8 * q);
#pragma unroll
      for (int s = 0; s < 2; ++s) {
        short8 bw = *(const short8*)(Wl + (n0 + s * 16 + r) * NDIM + k0 + 8 * q);
#pragma unroll
        for (int mt = 0; mt < 4; ++mt)
          acc[s][mt] = __builtin_amdgcn_mfma_f32_16x16x32_bf16(ah[mt], bw, acc[s][mt], 0, 0, 0);
      }
    }

    // ---- relu -> packed bf16 in registers ----
    unsigned zc[2][4][2];   // [slab][mt: node tile][node pair within quad-rows]
#pragma unroll
    for (int s = 0; s < 2; ++s)
#pragma unroll
      for (int mt = 0; mt < 4; ++mt) {
        f32x4 a = acc[s][mt];
        zc[s][mt][0] = pkbf(fmaxf(a[0], 0.f), fmaxf(a[1], 0.f));
        zc[s][mt][1] = pkbf(fmaxf(a[2], 0.f), fmaxf(a[3], 0.f));
      }

    // ---- m2: houtT[d in n0-region][node'] = zT * (I+A)^T ----
    // transpose: permlane16_swap pre-mixes lo/hi mt pairs, then 4 bijective
    // bpermutes assemble the A-frag (16 bperm + 8 swap/wave-layer total).
    f32x4 acc2[2][4];
#pragma unroll
    for (int s = 0; s < 2; ++s)
#pragma unroll
      for (int nt = 0; nt < 4; ++nt) acc2[s][nt] = (f32x4){0.f, 0.f, 0.f, 0.f};
#pragma unroll
    for (int s = 0; s < 2; ++s) {
#pragma unroll
      for (int kh = 0; kh < 2; ++kh) {
        unsigned x0 = zc[s][2 * kh][0], y0 = zc[s][2 * kh + 1][0];
        unsigned x1 = zc[s][2 * kh][1], y1 = zc[s][2 * kh + 1][1];
        // d[16:31]<->s[0:15], d[48:63]<->s[32:47]
        asm("v_permlane16_swap_b32 %0, %1" : "+v"(x0), "+v"(y0));
        asm("v_permlane16_swap_b32 %0, %1" : "+v"(x1), "+v"(y1));
        S8 az;
        az.d[0] = (unsigned)__builtin_amdgcn_ds_bpermute(addrA, (int)x0);
        az.d[1] = (unsigned)__builtin_amdgcn_ds_bpermute(addrA, (int)x1);
        az.d[2] = (unsigned)__builtin_amdgcn_ds_bpermute(addrA, (int)y0);
        az.d[3] = (unsigned)__builtin_amdgcn_ds_bpermute(addrA, (int)y1);
#pragma unroll
        for (int nt = 0; nt < 4; ++nt)
          acc2[s][nt] = __builtin_amdgcn_mfma_f32_16x16x32_bf16(az.s8, fbr[kh][nt], acc2[s][nt], 0, 0, 0);
      }
    }

    __builtin_amdgcn_s_setprio(0);

    if (l < NLAYER - 1) {
      // write h into the OTHER buffer: no pre-barrier needed
#pragma unroll
      for (int s = 0; s < 2; ++s)
#pragma unroll
        for (int nt = 0; nt < 4; ++nt) {
          f32x4 a = acc2[s][nt];
          uint2 u = {pkbf(a[0], a[1]), pkbf(a[2], a[3])};
          *(uint2*)(shw + (nt * 16 + r) * PH + n0 + s * 16 + 4 * q) = u;
        }
      __syncthreads();   // single barrier per layer
    } else {
      // ---- sum-pool: out[g][d] = sum_node' h[node'][d] ----
#pragma unroll
      for (int s = 0; s < 2; ++s) {
        f32x4 sum;
#pragma unroll
        for (int i = 0; i < 4; ++i)
          sum[i] = acc2[s][0][i] + acc2[s][1][i] + acc2[s][2][i] + acc2[s][3][i];
#pragma unroll
        for (int m = 1; m <= 8; m <<= 1) {
          sum[0] += __shfl_xor(sum[0], m);
          sum[1] += __shfl_xor(sum[1], m);
          sum[2] += __shfl_xor(sum[2], m);
          sum[3] += __shfl_xor(sum[3], m);
        }
        if (r == 0) {
          float4 o = {sum[0], sum[1], sum[2], sum[3]};
          *(float4*)(out + (size_t)g * NDIM + n0 + s * 16 + 4 * q) = o;
        }
      }
    }
  }
}

extern "C" void kernel_launch(void* const* d_in, const int* in_sizes, int n_in,
                              void* d_out, int out_size, void* d_ws, size_t ws_size,
                              hipStream_t stream) {
  const int*   fps  = (const int*)d_in[0];
  const float* adj  = (const float*)d_in[1];
  const float* emb  = (const float*)d_in[2];
  const float* W    = (const float*)d_in[3];
  const float* bias = (const float*)d_in[4];
  float* out = (float*)d_out;

  hipLaunchKernelGGL(convert_w, dim3(192), dim3(256), 0, stream, W);
  hipLaunchKernelGGL(convert_emb, dim3(1024), dim3(256), 0, stream, emb);
  hipLaunchKernelGGL(mpnn_mfma, dim3(NGRAPH), dim3(256), 0, stream,
                     fps, adj, emb, bias, out);
}